// Round 5
// baseline (558.676 us; speedup 1.0000x reference)
//
#include <hip/hip_runtime.h>
#include <math.h>

typedef __bf16 bf16x8v __attribute__((ext_vector_type(8)));
typedef short bf16x4s __attribute__((ext_vector_type(4)));
typedef float f32x4 __attribute__((ext_vector_type(4)));

__device__ __forceinline__ void async_copy16(void* lds, const void* g) {
  __builtin_amdgcn_global_load_lds(
      (const __attribute__((address_space(1))) void*)g,
      (__attribute__((address_space(3))) void*)lds, 16, 0, 0);
}

// ---- f32 -> bf16 cast, all 7 tensors in one launch ----
struct CastArgs {
  const float* s[7];
  __bf16* d[7];
};
__global__ __launch_bounds__(256) void cast_kernel(CastArgs a) {
  const int t = blockIdx.y;
  const int n = (t < 3) ? 8388608 : 1048576;
  const int i = (blockIdx.x * 256 + threadIdx.x) * 8;
  if (i >= n) return;
  const float4 v0 = *(const float4*)(a.s[t] + i);
  const float4 v1 = *(const float4*)(a.s[t] + i + 4);
  bf16x8v o;
  o[0] = (__bf16)v0.x; o[1] = (__bf16)v0.y; o[2] = (__bf16)v0.z; o[3] = (__bf16)v0.w;
  o[4] = (__bf16)v1.x; o[5] = (__bf16)v1.y; o[6] = (__bf16)v1.z; o[7] = (__bf16)v1.w;
  *(bf16x8v*)(a.d[t] + i) = o;
}

// C[m,n] = sum_k A[m,k] * B[n,k]   (A: MxK row-major, B: NxK row-major, bf16)
// LDS tiles XOR-swizzled at 16B-block granularity (see round-3 notes).
// MODE 0: C[row*N+col] (float, final output)
// MODE 1: split heads -> [B,H,S,dk]  (row=b*2048+s, col=h*64+d)
// MODE 3: V^T heads -> [B,H,dk,S]    (row=h*64+d [M=1024], col=b*2048+s [N=8192])
template <int MODE, typename OutT>
__global__ __launch_bounds__(256) void gemm_bt(const __bf16* __restrict__ A,
                                               const __bf16* __restrict__ B,
                                               OutT* __restrict__ C,
                                               int M, int N, int K) {
  __shared__ __bf16 As[128 * 64];
  __shared__ __bf16 Bs[128 * 64];
  const int tid = threadIdx.x;
  const int wave = tid >> 6, lane = tid & 63;
  const int lgrp = lane >> 4, lmod = lane & 15;
  const int bm = blockIdx.y * 128, bn = blockIdx.x * 128;
  const int wm = (wave >> 1) * 64, wn = (wave & 1) * 64;

  f32x4 acc[4][4];
#pragma unroll
  for (int mi = 0; mi < 4; mi++)
#pragma unroll
    for (int ni = 0; ni < 4; ni++)
#pragma unroll
      for (int r = 0; r < 4; r++) acc[mi][ni][r] = 0.f;

  for (int kt = 0; kt < K; kt += 64) {
#pragma unroll
    for (int i = 0; i < 4; i++) {
      const int s = i * 256 + tid;      // 16B-block slot in 128x8-block tile
      const int r = s >> 3, cb = s & 7;
      const int gc = (cb ^ (r & 7)) * 8;  // swizzled global column (elements)
      async_copy16(&As[s * 8], &A[(size_t)(bm + r) * K + kt + gc]);
      async_copy16(&Bs[s * 8], &B[(size_t)(bn + r) * K + kt + gc]);
    }
    __syncthreads();
#pragma unroll
    for (int ks = 0; ks < 2; ks++) {
      bf16x8v af[4], bf[4];
#pragma unroll
      for (int mi = 0; mi < 4; mi++) {
        const int row = wm + mi * 16 + lmod;
        af[mi] = *(const bf16x8v*)&As[row * 64 + ((ks * 4 + lgrp) ^ (row & 7)) * 8];
      }
#pragma unroll
      for (int ni = 0; ni < 4; ni++) {
        const int row = wn + ni * 16 + lmod;
        bf[ni] = *(const bf16x8v*)&Bs[row * 64 + ((ks * 4 + lgrp) ^ (row & 7)) * 8];
      }
#pragma unroll
      for (int mi = 0; mi < 4; mi++)
#pragma unroll
        for (int ni = 0; ni < 4; ni++)
          acc[mi][ni] = __builtin_amdgcn_mfma_f32_16x16x32_bf16(af[mi], bf[ni],
                                                                acc[mi][ni], 0, 0, 0);
    }
    __syncthreads();
  }

#pragma unroll
  for (int mi = 0; mi < 4; mi++)
#pragma unroll
    for (int ni = 0; ni < 4; ni++)
#pragma unroll
      for (int r = 0; r < 4; r++) {
        const int row = bm + wm + mi * 16 + lgrp * 4 + r;
        const int col = bn + wn + ni * 16 + lmod;
        if (MODE == 0) {
          C[(size_t)row * N + col] = (OutT)acc[mi][ni][r];
        } else if (MODE == 1) {
          C[(size_t)(row >> 11) * 2097152 + (size_t)(col >> 6) * 131072 +
            (size_t)(row & 2047) * 64 + (col & 63)] = (OutT)acc[mi][ni][r];
        } else {  // MODE 3: Vt[b][h][d][s], row=h*64+d, col=b*2048+s (coalesced in s)
          C[(size_t)(col >> 11) * 2097152 + (size_t)(row >> 6) * 131072 +
            (size_t)(row & 63) * 2048 + (col & 2047)] = (OutT)acc[mi][ni][r];
        }
      }
}

// Flash attention, S^T formulation (P never touches LDS).
// Qh,Kh: [B,H,S,dk]; Vt: [B,H,dk,S]; O: [B,S,H*dk]  (all bf16)
// grid: (16 q-tiles, 64 b*h), block 256 (4 waves x 32 q-rows)
// S^T = K*Q^T via mfma(A=K, B=Q): C/D has q in lanes (col=lmod), kv in regs.
// kv processed in 64-wide sub-chunks so st[] stays at 32 VGPRs -> fits the
// 128-reg cap of (256,4) WITHOUT SPILLING (round-4 spilled 1.1GB to scratch).
__global__ __launch_bounds__(256, 4) void attn_kernel(const __bf16* __restrict__ Qh,
                                                      const __bf16* __restrict__ Kh,
                                                      const __bf16* __restrict__ Vt,
                                                      __bf16* __restrict__ O) {
  __shared__ __bf16 Ks[128 * 64];    // [kv][d], XOR-swizzled 16B blocks
  __shared__ __bf16 Vts[64 * 128];   // [d][kv], XOR-swizzled 16B blocks

  const int tid = threadIdx.x;
  const int wave = tid >> 6, lane = tid & 63;
  const int lgrp = lane >> 4, lmod = lane & 15;
  const int qt = blockIdx.x, y = blockIdx.y;  // y = b*16+h
  const size_t hb = (size_t)y * 131072;
  const __bf16* Qb = Qh + hb + (size_t)qt * 128 * 64;
  const __bf16* Kb = Kh + hb;
  const __bf16* Vb = Vt + hb;
  const int wq0 = wave * 32;

  // Q fragments (B-operand: n=q=lmod, k=d), pre-scaled by 0.125*log2(e)
  const float qscale = 0.125f * 1.44269504f;
  bf16x8v qf[2][2];  // [qtile][ks]
#pragma unroll
  for (int qi = 0; qi < 2; qi++)
#pragma unroll
    for (int ks = 0; ks < 2; ks++) {
      bf16x8v q = *(const bf16x8v*)&Qb[(wq0 + qi * 16 + lmod) * 64 + ks * 32 + lgrp * 8];
#pragma unroll
      for (int j = 0; j < 8; j++) q[j] = (__bf16)((float)q[j] * qscale);
      qf[qi][ks] = q;
    }

  // softmax state for q = wq0 + qi*16 + lmod (per-lane, 2 rows)
  float m_run[2] = {-INFINITY, -INFINITY};
  float l_run[2] = {0.f, 0.f};
  f32x4 oacc[2][4];  // [qtile][dtile]; col=d=lmod, row=q=lgrp*4+r
#pragma unroll
  for (int qi = 0; qi < 2; qi++)
#pragma unroll
    for (int nd = 0; nd < 4; nd++)
#pragma unroll
      for (int r = 0; r < 4; r++) oacc[qi][nd][r] = 0.f;

  for (int kv0 = 0; kv0 < 2048; kv0 += 128) {
#pragma unroll
    for (int i = 0; i < 4; i++) {
      const int s = i * 256 + tid;
      {  // Ks: 128 rows x 8 blocks
        const int r = s >> 3, cb = s & 7;
        async_copy16(&Ks[s * 8], &Kb[(size_t)(kv0 + r) * 64 + (cb ^ (r & 7)) * 8]);
      }
      {  // Vts: 64 rows x 16 blocks
        const int r = s >> 4, cb = s & 15;
        async_copy16(&Vts[s * 8], &Vb[(size_t)r * 2048 + kv0 + (cb ^ (r & 7)) * 8]);
      }
    }
    __syncthreads();

#pragma unroll
    for (int half = 0; half < 2; half++) {
      // S^T = K Q^T over 64 kv: st[kvtile][qtile], col=q=lmod, row=kv
      f32x4 st[4][2];
#pragma unroll
      for (int t = 0; t < 4; t++)
#pragma unroll
        for (int qi = 0; qi < 2; qi++)
#pragma unroll
          for (int r = 0; r < 4; r++) st[t][qi][r] = 0.f;
#pragma unroll
      for (int ks = 0; ks < 2; ks++) {
#pragma unroll
        for (int t = 0; t < 4; t++) {
          const int row = half * 64 + t * 16 + lmod;
          const bf16x8v kf =
              *(const bf16x8v*)&Ks[row * 64 + ((ks * 4 + lgrp) ^ (row & 7)) * 8];
#pragma unroll
          for (int qi = 0; qi < 2; qi++)
            st[t][qi] = __builtin_amdgcn_mfma_f32_16x16x32_bf16(kf, qf[qi][ks],
                                                                st[t][qi], 0, 0, 0);
        }
      }

      // online-softmax update over this 64-kv sub-chunk
      float alpha_l[2], mnew_l[2];
#pragma unroll
      for (int qi = 0; qi < 2; qi++) {
        float rmax = st[0][qi][0];
#pragma unroll
        for (int t = 0; t < 4; t++)
#pragma unroll
          for (int r = 0; r < 4; r++) rmax = fmaxf(rmax, st[t][qi][r]);
        rmax = fmaxf(rmax, __shfl_xor(rmax, 16));
        rmax = fmaxf(rmax, __shfl_xor(rmax, 32));
        const float mnew = fmaxf(m_run[qi], rmax);
        alpha_l[qi] = __builtin_amdgcn_exp2f(m_run[qi] - mnew);
        mnew_l[qi] = mnew;
        m_run[qi] = mnew;
      }
      // broadcast alpha from stat-lanes (lmod=q) to O-rows (q=lgrp*4+r)
#pragma unroll
      for (int qi = 0; qi < 2; qi++)
#pragma unroll
        for (int r = 0; r < 4; r++) {
          const float ar = __shfl(alpha_l[qi], lgrp * 4 + r);
#pragma unroll
          for (int nd = 0; nd < 4; nd++) oacc[qi][nd][r] *= ar;
        }

      // PV: exp2 on the fly; P^T fragment feeds mfma_16x16x16 A-operand directly
      float psum[2] = {0.f, 0.f};
#pragma unroll
      for (int t = 0; t < 4; t++) {
        bf16x4s vf[4];  // B-operand: n=d=lmod, k=kv
        const int kvb = half * 64 + t * 16 + lgrp * 4;
#pragma unroll
        for (int nd = 0; nd < 4; nd++) {
          const int row = nd * 16 + lmod;
          vf[nd] =
              *(const bf16x4s*)&Vts[row * 128 + ((kvb >> 3) ^ (row & 7)) * 8 + (kvb & 7)];
        }
#pragma unroll
        for (int qi = 0; qi < 2; qi++) {
          union { __bf16 b[4]; bf16x4s s; } pf;
#pragma unroll
          for (int r = 0; r < 4; r++) {
            const float p = __builtin_amdgcn_exp2f(st[t][qi][r] - mnew_l[qi]);
            psum[qi] += p;
            pf.b[r] = (__bf16)p;
          }
#pragma unroll
          for (int nd = 0; nd < 4; nd++)
            oacc[qi][nd] = __builtin_amdgcn_mfma_f32_16x16x16bf16_1k(pf.s, vf[nd],
                                                                     oacc[qi][nd], 0, 0, 0);
        }
      }
#pragma unroll
      for (int qi = 0; qi < 2; qi++) {
        float ps = psum[qi];
        ps += __shfl_xor(ps, 16);
        ps += __shfl_xor(ps, 32);
        l_run[qi] = l_run[qi] * alpha_l[qi] + ps;
      }
    }
    __syncthreads();  // protect Ks/Vts before next stage
  }

  const int b = y >> 4, h = y & 15;
#pragma unroll
  for (int qi = 0; qi < 2; qi++) {
    const float linv = 1.f / l_run[qi];
#pragma unroll
    for (int r = 0; r < 4; r++) {
      const float inv = __shfl(linv, lgrp * 4 + r);
      const int srow = qt * 128 + wq0 + qi * 16 + lgrp * 4 + r;
      const size_t base = ((size_t)(b * 2048 + srow)) * 1024 + h * 64;
#pragma unroll
      for (int nd = 0; nd < 4; nd++)
        O[base + nd * 16 + lmod] = (__bf16)(oacc[qi][nd][r] * inv);
    }
  }
}

extern "C" void kernel_launch(void* const* d_in, const int* in_sizes, int n_in,
                              void* d_out, int out_size, void* d_ws, size_t ws_size,
                              hipStream_t stream) {
  const float* Qin = (const float*)d_in[0];
  const float* Kin = (const float*)d_in[1];
  const float* Vin = (const float*)d_in[2];
  const float* Wq = (const float*)d_in[3];
  const float* Wk = (const float*)d_in[4];
  const float* Wv = (const float*)d_in[5];
  const float* Wo = (const float*)d_in[6];
  float* out = (float*)d_out;

  __bf16* base = (__bf16*)d_ws;
  __bf16* Qbf = base;                    // 8388608
  __bf16* Kbf = base + 8388608;
  __bf16* Vbf = base + 16777216;
  __bf16* Wqb = base + 25165824;         // 1048576 each
  __bf16* Wkb = base + 26214400;
  __bf16* Wvb = base + 27262976;
  __bf16* Wob = base + 28311552;
  __bf16* Qh = base + 29360128;          // [B,H,S,dk]
  __bf16* Kh = base + 37748736;          // [B,H,S,dk]
  __bf16* Vt = base + 46137344;          // [B,H,dk,S]
  __bf16* AO = Qbf;                      // aliases Qbf (dead after gemm1)

  CastArgs ca;
  ca.s[0] = Qin; ca.s[1] = Kin; ca.s[2] = Vin;
  ca.s[3] = Wq;  ca.s[4] = Wk;  ca.s[5] = Wv;  ca.s[6] = Wo;
  ca.d[0] = Qbf; ca.d[1] = Kbf; ca.d[2] = Vbf;
  ca.d[3] = Wqb; ca.d[4] = Wkb; ca.d[5] = Wvb; ca.d[6] = Wob;
  cast_kernel<<<dim3(4096, 7), 256, 0, stream>>>(ca);

  const int M = 8192, N = 1024, K = 1024;
  dim3 bb(256);
  gemm_bt<1, __bf16><<<dim3(8, 64), bb, 0, stream>>>(Qbf, Wqb, Qh, M, N, K);
  gemm_bt<1, __bf16><<<dim3(8, 64), bb, 0, stream>>>(Kbf, Wkb, Kh, M, N, K);
  // V^T: swap operands -> Vt[n][s] = sum_k Wv[n][k] * Vin[s][k]  (M=1024, N=8192)
  gemm_bt<3, __bf16><<<dim3(64, 8), bb, 0, stream>>>(Wvb, Vbf, Vt, 1024, 8192, K);
  attn_kernel<<<dim3(16, 64), bb, 0, stream>>>(Qh, Kh, Vt, AO);
  gemm_bt<0, float><<<dim3(8, 64), bb, 0, stream>>>(AO, Wob, out, M, N, K);
}

// Round 6
// 392.644 us; speedup vs baseline: 1.4229x; 1.4229x over previous
//
#include <hip/hip_runtime.h>
#include <math.h>

typedef __bf16 bf16x8v __attribute__((ext_vector_type(8)));
typedef short bf16x4s __attribute__((ext_vector_type(4)));
typedef float f32x4 __attribute__((ext_vector_type(4)));

__device__ __forceinline__ void async_copy16(void* lds, const void* g) {
  __builtin_amdgcn_global_load_lds(
      (const __attribute__((address_space(1))) void*)g,
      (__attribute__((address_space(3))) void*)lds, 16, 0, 0);
}

// ---- f32 -> bf16 cast, all 7 tensors in one launch ----
struct CastArgs {
  const float* s[7];
  __bf16* d[7];
};
__global__ __launch_bounds__(256) void cast_kernel(CastArgs a) {
  const int t = blockIdx.y;
  const int n = (t < 3) ? 8388608 : 1048576;
  const int i = (blockIdx.x * 256 + threadIdx.x) * 8;
  if (i >= n) return;
  const float4 v0 = *(const float4*)(a.s[t] + i);
  const float4 v1 = *(const float4*)(a.s[t] + i + 4);
  bf16x8v o;
  o[0] = (__bf16)v0.x; o[1] = (__bf16)v0.y; o[2] = (__bf16)v0.z; o[3] = (__bf16)v0.w;
  o[4] = (__bf16)v1.x; o[5] = (__bf16)v1.y; o[6] = (__bf16)v1.z; o[7] = (__bf16)v1.w;
  *(bf16x8v*)(a.d[t] + i) = o;
}

// C[m,n] = sum_k A[m,k] * B[n,k]   (A: MxK row-major, B: NxK row-major, bf16)
// LDS tiles XOR-swizzled at 16B-block granularity (see round-3 notes).
// MODE 0: C[row*N+col] (float, final output)
// MODE 1: split heads -> [B,H,S,dk]  (row=b*2048+s, col=h*64+d)
// MODE 3: V^T heads -> [B,H,dk,S]    (row=h*64+d [M=1024], col=b*2048+s [N=8192])
template <int MODE, typename OutT>
__global__ __launch_bounds__(256) void gemm_bt(const __bf16* __restrict__ A,
                                               const __bf16* __restrict__ B,
                                               OutT* __restrict__ C,
                                               int M, int N, int K) {
  __shared__ __bf16 As[128 * 64];
  __shared__ __bf16 Bs[128 * 64];
  const int tid = threadIdx.x;
  const int wave = tid >> 6, lane = tid & 63;
  const int lgrp = lane >> 4, lmod = lane & 15;
  const int bm = blockIdx.y * 128, bn = blockIdx.x * 128;
  const int wm = (wave >> 1) * 64, wn = (wave & 1) * 64;

  f32x4 acc[4][4];
#pragma unroll
  for (int mi = 0; mi < 4; mi++)
#pragma unroll
    for (int ni = 0; ni < 4; ni++)
#pragma unroll
      for (int r = 0; r < 4; r++) acc[mi][ni][r] = 0.f;

  for (int kt = 0; kt < K; kt += 64) {
#pragma unroll
    for (int i = 0; i < 4; i++) {
      const int s = i * 256 + tid;      // 16B-block slot in 128x8-block tile
      const int r = s >> 3, cb = s & 7;
      const int gc = (cb ^ (r & 7)) * 8;  // swizzled global column (elements)
      async_copy16(&As[s * 8], &A[(size_t)(bm + r) * K + kt + gc]);
      async_copy16(&Bs[s * 8], &B[(size_t)(bn + r) * K + kt + gc]);
    }
    __syncthreads();
#pragma unroll
    for (int ks = 0; ks < 2; ks++) {
      bf16x8v af[4], bf[4];
#pragma unroll
      for (int mi = 0; mi < 4; mi++) {
        const int row = wm + mi * 16 + lmod;
        af[mi] = *(const bf16x8v*)&As[row * 64 + ((ks * 4 + lgrp) ^ (row & 7)) * 8];
      }
#pragma unroll
      for (int ni = 0; ni < 4; ni++) {
        const int row = wn + ni * 16 + lmod;
        bf[ni] = *(const bf16x8v*)&Bs[row * 64 + ((ks * 4 + lgrp) ^ (row & 7)) * 8];
      }
#pragma unroll
      for (int mi = 0; mi < 4; mi++)
#pragma unroll
        for (int ni = 0; ni < 4; ni++)
          acc[mi][ni] = __builtin_amdgcn_mfma_f32_16x16x32_bf16(af[mi], bf[ni],
                                                                acc[mi][ni], 0, 0, 0);
    }
    __syncthreads();
  }

#pragma unroll
  for (int mi = 0; mi < 4; mi++)
#pragma unroll
    for (int ni = 0; ni < 4; ni++)
#pragma unroll
      for (int r = 0; r < 4; r++) {
        const int row = bm + wm + mi * 16 + lgrp * 4 + r;
        const int col = bn + wn + ni * 16 + lmod;
        if (MODE == 0) {
          C[(size_t)row * N + col] = (OutT)acc[mi][ni][r];
        } else if (MODE == 1) {
          C[(size_t)(row >> 11) * 2097152 + (size_t)(col >> 6) * 131072 +
            (size_t)(row & 2047) * 64 + (col & 63)] = (OutT)acc[mi][ni][r];
        } else {  // MODE 3: Vt[b][h][d][s], row=h*64+d, col=b*2048+s (coalesced in s)
          C[(size_t)(col >> 11) * 2097152 + (size_t)(row >> 6) * 131072 +
            (size_t)(row & 63) * 2048 + (col & 2047)] = (OutT)acc[mi][ni][r];
        }
      }
}

// Flash attention, S^T formulation (P never touches LDS).
// Qh,Kh: [B,H,S,dk]; Vt: [B,H,dk,S]; O: [B,S,H*dk]  (all bf16)
// grid: (16 q-tiles, 64 b*h), block 256 (4 waves x 32 q-rows)
// S^T = K*Q^T via mfma(A=K, B=Q): C/D has q in lanes (col=lmod), kv in regs.
// kv processed in 64-wide sub-chunks (REAL loop, not unrolled) to halve the
// peak live set. NO min-waves launch-bounds clamp: round-4/5's (256,4) forced
// a 128-reg unified cap -> 64 arch VGPRs after AGPR accumulators -> 1.2 GB of
// scratch spill traffic. Plain (256) let the compiler pick ~116 regs in r3.
__global__ __launch_bounds__(256) void attn_kernel(const __bf16* __restrict__ Qh,
                                                   const __bf16* __restrict__ Kh,
                                                   const __bf16* __restrict__ Vt,
                                                   __bf16* __restrict__ O) {
  __shared__ __bf16 Ks[128 * 64];    // [kv][d], XOR-swizzled 16B blocks
  __shared__ __bf16 Vts[64 * 128];   // [d][kv], XOR-swizzled 16B blocks

  const int tid = threadIdx.x;
  const int wave = tid >> 6, lane = tid & 63;
  const int lgrp = lane >> 4, lmod = lane & 15;
  const int qt = blockIdx.x, y = blockIdx.y;  // y = b*16+h
  const size_t hb = (size_t)y * 131072;
  const __bf16* Qb = Qh + hb + (size_t)qt * 128 * 64;
  const __bf16* Kb = Kh + hb;
  const __bf16* Vb = Vt + hb;
  const int wq0 = wave * 32;

  // Q fragments (B-operand: n=q=lmod, k=d), pre-scaled by 0.125*log2(e)
  const float qscale = 0.125f * 1.44269504f;
  bf16x8v qf[2][2];  // [qtile][ks]
#pragma unroll
  for (int qi = 0; qi < 2; qi++)
#pragma unroll
    for (int ks = 0; ks < 2; ks++) {
      bf16x8v q = *(const bf16x8v*)&Qb[(wq0 + qi * 16 + lmod) * 64 + ks * 32 + lgrp * 8];
#pragma unroll
      for (int j = 0; j < 8; j++) q[j] = (__bf16)((float)q[j] * qscale);
      qf[qi][ks] = q;
    }

  // softmax state for q = wq0 + qi*16 + lmod (per-lane, 2 rows)
  float m_run[2] = {-INFINITY, -INFINITY};
  float l_run[2] = {0.f, 0.f};
  f32x4 oacc[2][4];  // [qtile][dtile]; col=d=lmod, row=q=lgrp*4+r
#pragma unroll
  for (int qi = 0; qi < 2; qi++)
#pragma unroll
    for (int nd = 0; nd < 4; nd++)
#pragma unroll
      for (int r = 0; r < 4; r++) oacc[qi][nd][r] = 0.f;

  for (int kv0 = 0; kv0 < 2048; kv0 += 128) {
#pragma unroll
    for (int i = 0; i < 4; i++) {
      const int s = i * 256 + tid;
      {  // Ks: 128 rows x 8 blocks
        const int r = s >> 3, cb = s & 7;
        async_copy16(&Ks[s * 8], &Kb[(size_t)(kv0 + r) * 64 + (cb ^ (r & 7)) * 8]);
      }
      {  // Vts: 64 rows x 16 blocks
        const int r = s >> 4, cb = s & 15;
        async_copy16(&Vts[s * 8], &Vb[(size_t)r * 2048 + kv0 + (cb ^ (r & 7)) * 8]);
      }
    }
    __syncthreads();

#pragma unroll 1  // keep halves SEPARATE: merging doubles live registers
    for (int half = 0; half < 2; half++) {
      // S^T = K Q^T over 64 kv: st[kvtile][qtile], col=q=lmod, row=kv
      f32x4 st[4][2];
#pragma unroll
      for (int t = 0; t < 4; t++)
#pragma unroll
        for (int qi = 0; qi < 2; qi++)
#pragma unroll
          for (int r = 0; r < 4; r++) st[t][qi][r] = 0.f;
#pragma unroll
      for (int ks = 0; ks < 2; ks++) {
#pragma unroll
        for (int t = 0; t < 4; t++) {
          const int row = half * 64 + t * 16 + lmod;
          const bf16x8v kf =
              *(const bf16x8v*)&Ks[row * 64 + ((ks * 4 + lgrp) ^ (row & 7)) * 8];
#pragma unroll
          for (int qi = 0; qi < 2; qi++)
            st[t][qi] = __builtin_amdgcn_mfma_f32_16x16x32_bf16(kf, qf[qi][ks],
                                                                st[t][qi], 0, 0, 0);
        }
      }

      // online-softmax update over this 64-kv sub-chunk
      float alpha_l[2], mnew_l[2];
#pragma unroll
      for (int qi = 0; qi < 2; qi++) {
        float rmax = st[0][qi][0];
#pragma unroll
        for (int t = 0; t < 4; t++)
#pragma unroll
          for (int r = 0; r < 4; r++) rmax = fmaxf(rmax, st[t][qi][r]);
        rmax = fmaxf(rmax, __shfl_xor(rmax, 16));
        rmax = fmaxf(rmax, __shfl_xor(rmax, 32));
        const float mnew = fmaxf(m_run[qi], rmax);
        alpha_l[qi] = __builtin_amdgcn_exp2f(m_run[qi] - mnew);
        mnew_l[qi] = mnew;
        m_run[qi] = mnew;
      }
      // broadcast alpha from stat-lanes (lmod=q) to O-rows (q=lgrp*4+r)
#pragma unroll
      for (int qi = 0; qi < 2; qi++)
#pragma unroll
        for (int r = 0; r < 4; r++) {
          const float ar = __shfl(alpha_l[qi], lgrp * 4 + r);
#pragma unroll
          for (int nd = 0; nd < 4; nd++) oacc[qi][nd][r] *= ar;
        }

      // PV: exp2 on the fly; P^T fragment feeds mfma_16x16x16 A-operand directly
      float psum[2] = {0.f, 0.f};
#pragma unroll
      for (int t = 0; t < 4; t++) {
        bf16x4s vf[4];  // B-operand: n=d=lmod, k=kv
        const int kvb = half * 64 + t * 16 + lgrp * 4;
#pragma unroll
        for (int nd = 0; nd < 4; nd++) {
          const int row = nd * 16 + lmod;
          vf[nd] =
              *(const bf16x4s*)&Vts[row * 128 + ((kvb >> 3) ^ (row & 7)) * 8 + (kvb & 7)];
        }
#pragma unroll
        for (int qi = 0; qi < 2; qi++) {
          union { __bf16 b[4]; bf16x4s s; } pf;
#pragma unroll
          for (int r = 0; r < 4; r++) {
            const float p = __builtin_amdgcn_exp2f(st[t][qi][r] - mnew_l[qi]);
            psum[qi] += p;
            pf.b[r] = (__bf16)p;
          }
#pragma unroll
          for (int nd = 0; nd < 4; nd++)
            oacc[qi][nd] = __builtin_amdgcn_mfma_f32_16x16x16bf16_1k(pf.s, vf[nd],
                                                                     oacc[qi][nd], 0, 0, 0);
        }
      }
#pragma unroll
      for (int qi = 0; qi < 2; qi++) {
        float ps = psum[qi];
        ps += __shfl_xor(ps, 16);
        ps += __shfl_xor(ps, 32);
        l_run[qi] = l_run[qi] * alpha_l[qi] + ps;
      }
    }
    __syncthreads();  // protect Ks/Vts before next stage
  }

  const int b = y >> 4, h = y & 15;
#pragma unroll
  for (int qi = 0; qi < 2; qi++) {
    const float linv = 1.f / l_run[qi];
#pragma unroll
    for (int r = 0; r < 4; r++) {
      const float inv = __shfl(linv, lgrp * 4 + r);
      const int srow = qt * 128 + wq0 + qi * 16 + lgrp * 4 + r;
      const size_t base = ((size_t)(b * 2048 + srow)) * 1024 + h * 64;
#pragma unroll
      for (int nd = 0; nd < 4; nd++)
        O[base + nd * 16 + lmod] = (__bf16)(oacc[qi][nd][r] * inv);
    }
  }
}

extern "C" void kernel_launch(void* const* d_in, const int* in_sizes, int n_in,
                              void* d_out, int out_size, void* d_ws, size_t ws_size,
                              hipStream_t stream) {
  const float* Qin = (const float*)d_in[0];
  const float* Kin = (const float*)d_in[1];
  const float* Vin = (const float*)d_in[2];
  const float* Wq = (const float*)d_in[3];
  const float* Wk = (const float*)d_in[4];
  const float* Wv = (const float*)d_in[5];
  const float* Wo = (const float*)d_in[6];
  float* out = (float*)d_out;

  __bf16* base = (__bf16*)d_ws;
  __bf16* Qbf = base;                    // 8388608
  __bf16* Kbf = base + 8388608;
  __bf16* Vbf = base + 16777216;
  __bf16* Wqb = base + 25165824;         // 1048576 each
  __bf16* Wkb = base + 26214400;
  __bf16* Wvb = base + 27262976;
  __bf16* Wob = base + 28311552;
  __bf16* Qh = base + 29360128;          // [B,H,S,dk]
  __bf16* Kh = base + 37748736;          // [B,H,S,dk]
  __bf16* Vt = base + 46137344;          // [B,H,dk,S]
  __bf16* AO = Qbf;                      // aliases Qbf (dead after gemm1)

  CastArgs ca;
  ca.s[0] = Qin; ca.s[1] = Kin; ca.s[2] = Vin;
  ca.s[3] = Wq;  ca.s[4] = Wk;  ca.s[5] = Wv;  ca.s[6] = Wo;
  ca.d[0] = Qbf; ca.d[1] = Kbf; ca.d[2] = Vbf;
  ca.d[3] = Wqb; ca.d[4] = Wkb; ca.d[5] = Wvb; ca.d[6] = Wob;
  cast_kernel<<<dim3(4096, 7), 256, 0, stream>>>(ca);

  const int M = 8192, N = 1024, K = 1024;
  dim3 bb(256);
  gemm_bt<1, __bf16><<<dim3(8, 64), bb, 0, stream>>>(Qbf, Wqb, Qh, M, N, K);
  gemm_bt<1, __bf16><<<dim3(8, 64), bb, 0, stream>>>(Kbf, Wkb, Kh, M, N, K);
  // V^T: swap operands -> Vt[n][s] = sum_k Wv[n][k] * Vin[s][k]  (M=1024, N=8192)
  gemm_bt<3, __bf16><<<dim3(64, 8), bb, 0, stream>>>(Wvb, Vbf, Vt, 1024, 8192, K);
  attn_kernel<<<dim3(16, 64), bb, 0, stream>>>(Qh, Kh, Vt, AO);
  gemm_bt<0, float><<<dim3(8, 64), bb, 0, stream>>>(AO, Wob, out, M, N, K);
}

// Round 7
// 389.759 us; speedup vs baseline: 1.4334x; 1.0074x over previous
//
#include <hip/hip_runtime.h>
#include <math.h>

typedef __bf16 bf16x8v __attribute__((ext_vector_type(8)));
typedef short bf16x4s __attribute__((ext_vector_type(4)));
typedef float f32x4 __attribute__((ext_vector_type(4)));

__device__ __forceinline__ void async_copy16(void* lds, const void* g) {
  __builtin_amdgcn_global_load_lds(
      (const __attribute__((address_space(1))) void*)g,
      (__attribute__((address_space(3))) void*)lds, 16, 0, 0);
}

// ---- f32 -> bf16 cast, all 7 tensors in one launch ----
struct CastArgs {
  const float* s[7];
  __bf16* d[7];
};
__global__ __launch_bounds__(256) void cast_kernel(CastArgs a) {
  const int t = blockIdx.y;
  const int n = (t < 3) ? 8388608 : 1048576;
  const int i = (blockIdx.x * 256 + threadIdx.x) * 8;
  if (i >= n) return;
  const float4 v0 = *(const float4*)(a.s[t] + i);
  const float4 v1 = *(const float4*)(a.s[t] + i + 4);
  bf16x8v o;
  o[0] = (__bf16)v0.x; o[1] = (__bf16)v0.y; o[2] = (__bf16)v0.z; o[3] = (__bf16)v0.w;
  o[4] = (__bf16)v1.x; o[5] = (__bf16)v1.y; o[6] = (__bf16)v1.z; o[7] = (__bf16)v1.w;
  *(bf16x8v*)(a.d[t] + i) = o;
}

// C[m,n] = sum_k A[m,k] * B[n,k]   (A: MxK row-major, B: NxK row-major, bf16)
// LDS tiles XOR-swizzled at 16B-block granularity (see round-3 notes).
// XCD locality: blocks are round-robined to the 8 XCDs by linear block id.
// For MODE 0/1 the LARGE operand is A (8192xK, indexed by bm) -> bm must
// determine the XCD: grid (bm=64, bn=8[, z]) gives linear%8 = bm%8, so all 8
// bn-blocks sharing an A row-block land on ONE XCD (A fetched once from HBM,
// was 8x = 134 MB/GEMM in r6). MODE 3's large operand is B (indexed by bn =
// blockIdx.x, grid (64,8)) -- already the good orientation.
// blockIdx.z selects the (A2,B2,C2) set (batched Q+K projections).
// MODE 0: C[row*N+col] (float, final output)
// MODE 1: split heads -> [B,H,S,dk]  (row=b*2048+s, col=h*64+d)
// MODE 3: V^T heads -> [B,H,dk,S]    (row=h*64+d [M=1024], col=b*2048+s [N=8192])
template <int MODE, typename OutT>
__global__ __launch_bounds__(256) void gemm_bt(const __bf16* A, const __bf16* B,
                                               OutT* C,
                                               const __bf16* A2, const __bf16* B2,
                                               OutT* C2,
                                               int M, int N, int K) {
  __shared__ __bf16 As[128 * 64];
  __shared__ __bf16 Bs[128 * 64];
  if (blockIdx.z == 1) { A = A2; B = B2; C = C2; }
  const int tid = threadIdx.x;
  const int wave = tid >> 6, lane = tid & 63;
  const int lgrp = lane >> 4, lmod = lane & 15;
  const int bm = (MODE == 3 ? blockIdx.y : blockIdx.x) * 128;
  const int bn = (MODE == 3 ? blockIdx.x : blockIdx.y) * 128;
  const int wm = (wave >> 1) * 64, wn = (wave & 1) * 64;

  f32x4 acc[4][4];
#pragma unroll
  for (int mi = 0; mi < 4; mi++)
#pragma unroll
    for (int ni = 0; ni < 4; ni++)
#pragma unroll
      for (int r = 0; r < 4; r++) acc[mi][ni][r] = 0.f;

  for (int kt = 0; kt < K; kt += 64) {
#pragma unroll
    for (int i = 0; i < 4; i++) {
      const int s = i * 256 + tid;      // 16B-block slot in 128x8-block tile
      const int r = s >> 3, cb = s & 7;
      const int gc = (cb ^ (r & 7)) * 8;  // swizzled global column (elements)
      async_copy16(&As[s * 8], &A[(size_t)(bm + r) * K + kt + gc]);
      async_copy16(&Bs[s * 8], &B[(size_t)(bn + r) * K + kt + gc]);
    }
    __syncthreads();
#pragma unroll
    for (int ks = 0; ks < 2; ks++) {
      bf16x8v af[4], bf[4];
#pragma unroll
      for (int mi = 0; mi < 4; mi++) {
        const int row = wm + mi * 16 + lmod;
        af[mi] = *(const bf16x8v*)&As[row * 64 + ((ks * 4 + lgrp) ^ (row & 7)) * 8];
      }
#pragma unroll
      for (int ni = 0; ni < 4; ni++) {
        const int row = wn + ni * 16 + lmod;
        bf[ni] = *(const bf16x8v*)&Bs[row * 64 + ((ks * 4 + lgrp) ^ (row & 7)) * 8];
      }
#pragma unroll
      for (int mi = 0; mi < 4; mi++)
#pragma unroll
        for (int ni = 0; ni < 4; ni++)
          acc[mi][ni] = __builtin_amdgcn_mfma_f32_16x16x32_bf16(af[mi], bf[ni],
                                                                acc[mi][ni], 0, 0, 0);
    }
    __syncthreads();
  }

#pragma unroll
  for (int mi = 0; mi < 4; mi++)
#pragma unroll
    for (int ni = 0; ni < 4; ni++)
#pragma unroll
      for (int r = 0; r < 4; r++) {
        const int row = bm + wm + mi * 16 + lgrp * 4 + r;
        const int col = bn + wn + ni * 16 + lmod;
        if (MODE == 0) {
          C[(size_t)row * N + col] = (OutT)acc[mi][ni][r];
        } else if (MODE == 1) {
          C[(size_t)(row >> 11) * 2097152 + (size_t)(col >> 6) * 131072 +
            (size_t)(row & 2047) * 64 + (col & 63)] = (OutT)acc[mi][ni][r];
        } else {  // MODE 3: Vt[b][h][d][s], row=h*64+d, col=b*2048+s (coalesced in s)
          C[(size_t)(col >> 11) * 2097152 + (size_t)(row >> 6) * 131072 +
            (size_t)(row & 63) * 2048 + (col & 2047)] = (OutT)acc[mi][ni][r];
        }
      }
}

// Flash attention, S^T formulation (P never touches LDS).
// Qh,Kh: [B,H,S,dk]; Vt: [B,H,dk,S]; O: [B,S,H*dk]  (all bf16)
// grid: (64 b*h, 16 q-tiles) -- y in blockIdx.x so linear%8 = y%8: all 16
// q-tile blocks sharing one head's K/V land on the same XCD (L2 reuse).
// block 256 (4 waves x 32 q-rows).
// S^T = K*Q^T via mfma(A=K, B=Q): C/D has q in lanes (col=lmod), kv in regs.
// kv processed in 64-wide sub-chunks (REAL loop, not unrolled) to halve the
// peak live set. NO min-waves launch-bounds clamp (r4/r5: (256,4) forced a
// 128-reg unified cap -> spill -> 1.2 GB scratch traffic).
__global__ __launch_bounds__(256) void attn_kernel(const __bf16* __restrict__ Qh,
                                                   const __bf16* __restrict__ Kh,
                                                   const __bf16* __restrict__ Vt,
                                                   __bf16* __restrict__ O) {
  __shared__ __bf16 Ks[128 * 64];    // [kv][d], XOR-swizzled 16B blocks
  __shared__ __bf16 Vts[64 * 128];   // [d][kv], XOR-swizzled 16B blocks

  const int tid = threadIdx.x;
  const int wave = tid >> 6, lane = tid & 63;
  const int lgrp = lane >> 4, lmod = lane & 15;
  const int qt = blockIdx.y, y = blockIdx.x;  // y = b*16+h
  const size_t hb = (size_t)y * 131072;
  const __bf16* Qb = Qh + hb + (size_t)qt * 128 * 64;
  const __bf16* Kb = Kh + hb;
  const __bf16* Vb = Vt + hb;
  const int wq0 = wave * 32;

  // Q fragments (B-operand: n=q=lmod, k=d), pre-scaled by 0.125*log2(e)
  const float qscale = 0.125f * 1.44269504f;
  bf16x8v qf[2][2];  // [qtile][ks]
#pragma unroll
  for (int qi = 0; qi < 2; qi++)
#pragma unroll
    for (int ks = 0; ks < 2; ks++) {
      bf16x8v q = *(const bf16x8v*)&Qb[(wq0 + qi * 16 + lmod) * 64 + ks * 32 + lgrp * 8];
#pragma unroll
      for (int j = 0; j < 8; j++) q[j] = (__bf16)((float)q[j] * qscale);
      qf[qi][ks] = q;
    }

  // softmax state for q = wq0 + qi*16 + lmod (per-lane, 2 rows)
  float m_run[2] = {-INFINITY, -INFINITY};
  float l_run[2] = {0.f, 0.f};
  f32x4 oacc[2][4];  // [qtile][dtile]; col=d=lmod, row=q=lgrp*4+r
#pragma unroll
  for (int qi = 0; qi < 2; qi++)
#pragma unroll
    for (int nd = 0; nd < 4; nd++)
#pragma unroll
      for (int r = 0; r < 4; r++) oacc[qi][nd][r] = 0.f;

  for (int kv0 = 0; kv0 < 2048; kv0 += 128) {
#pragma unroll
    for (int i = 0; i < 4; i++) {
      const int s = i * 256 + tid;
      {  // Ks: 128 rows x 8 blocks
        const int r = s >> 3, cb = s & 7;
        async_copy16(&Ks[s * 8], &Kb[(size_t)(kv0 + r) * 64 + (cb ^ (r & 7)) * 8]);
      }
      {  // Vts: 64 rows x 16 blocks
        const int r = s >> 4, cb = s & 15;
        async_copy16(&Vts[s * 8], &Vb[(size_t)r * 2048 + kv0 + (cb ^ (r & 7)) * 8]);
      }
    }
    __syncthreads();

#pragma unroll 1  // keep halves SEPARATE: merging doubles live registers
    for (int half = 0; half < 2; half++) {
      // S^T = K Q^T over 64 kv: st[kvtile][qtile], col=q=lmod, row=kv
      f32x4 st[4][2];
#pragma unroll
      for (int t = 0; t < 4; t++)
#pragma unroll
        for (int qi = 0; qi < 2; qi++)
#pragma unroll
          for (int r = 0; r < 4; r++) st[t][qi][r] = 0.f;
#pragma unroll
      for (int ks = 0; ks < 2; ks++) {
#pragma unroll
        for (int t = 0; t < 4; t++) {
          const int row = half * 64 + t * 16 + lmod;
          const bf16x8v kf =
              *(const bf16x8v*)&Ks[row * 64 + ((ks * 4 + lgrp) ^ (row & 7)) * 8];
#pragma unroll
          for (int qi = 0; qi < 2; qi++)
            st[t][qi] = __builtin_amdgcn_mfma_f32_16x16x32_bf16(kf, qf[qi][ks],
                                                                st[t][qi], 0, 0, 0);
        }
      }

      // online-softmax update over this 64-kv sub-chunk
      float alpha_l[2], mnew_l[2];
#pragma unroll
      for (int qi = 0; qi < 2; qi++) {
        float rmax = st[0][qi][0];
#pragma unroll
        for (int t = 0; t < 4; t++)
#pragma unroll
          for (int r = 0; r < 4; r++) rmax = fmaxf(rmax, st[t][qi][r]);
        rmax = fmaxf(rmax, __shfl_xor(rmax, 16));
        rmax = fmaxf(rmax, __shfl_xor(rmax, 32));
        const float mnew = fmaxf(m_run[qi], rmax);
        alpha_l[qi] = __builtin_amdgcn_exp2f(m_run[qi] - mnew);
        mnew_l[qi] = mnew;
        m_run[qi] = mnew;
      }
      // broadcast alpha from stat-lanes (lmod=q) to O-rows (q=lgrp*4+r)
#pragma unroll
      for (int qi = 0; qi < 2; qi++)
#pragma unroll
        for (int r = 0; r < 4; r++) {
          const float ar = __shfl(alpha_l[qi], lgrp * 4 + r);
#pragma unroll
          for (int nd = 0; nd < 4; nd++) oacc[qi][nd][r] *= ar;
        }

      // PV: exp2 on the fly; P^T fragment feeds mfma_16x16x16 A-operand directly
      float psum[2] = {0.f, 0.f};
#pragma unroll
      for (int t = 0; t < 4; t++) {
        bf16x4s vf[4];  // B-operand: n=d=lmod, k=kv
        const int kvb = half * 64 + t * 16 + lgrp * 4;
#pragma unroll
        for (int nd = 0; nd < 4; nd++) {
          const int row = nd * 16 + lmod;
          vf[nd] =
              *(const bf16x4s*)&Vts[row * 128 + ((kvb >> 3) ^ (row & 7)) * 8 + (kvb & 7)];
        }
#pragma unroll
        for (int qi = 0; qi < 2; qi++) {
          union { __bf16 b[4]; bf16x4s s; } pf;
#pragma unroll
          for (int r = 0; r < 4; r++) {
            const float p = __builtin_amdgcn_exp2f(st[t][qi][r] - mnew_l[qi]);
            psum[qi] += p;
            pf.b[r] = (__bf16)p;
          }
#pragma unroll
          for (int nd = 0; nd < 4; nd++)
            oacc[qi][nd] = __builtin_amdgcn_mfma_f32_16x16x16bf16_1k(pf.s, vf[nd],
                                                                     oacc[qi][nd], 0, 0, 0);
        }
      }
#pragma unroll
      for (int qi = 0; qi < 2; qi++) {
        float ps = psum[qi];
        ps += __shfl_xor(ps, 16);
        ps += __shfl_xor(ps, 32);
        l_run[qi] = l_run[qi] * alpha_l[qi] + ps;
      }
    }
    __syncthreads();  // protect Ks/Vts before next stage
  }

  const int b = y >> 4, h = y & 15;
#pragma unroll
  for (int qi = 0; qi < 2; qi++) {
    const float linv = 1.f / l_run[qi];
#pragma unroll
    for (int r = 0; r < 4; r++) {
      const float inv = __shfl(linv, lgrp * 4 + r);
      const int srow = qt * 128 + wq0 + qi * 16 + lgrp * 4 + r;
      const size_t base = ((size_t)(b * 2048 + srow)) * 1024 + h * 64;
#pragma unroll
      for (int nd = 0; nd < 4; nd++)
        O[base + nd * 16 + lmod] = (__bf16)(oacc[qi][nd][r] * inv);
    }
  }
}

extern "C" void kernel_launch(void* const* d_in, const int* in_sizes, int n_in,
                              void* d_out, int out_size, void* d_ws, size_t ws_size,
                              hipStream_t stream) {
  const float* Qin = (const float*)d_in[0];
  const float* Kin = (const float*)d_in[1];
  const float* Vin = (const float*)d_in[2];
  const float* Wq = (const float*)d_in[3];
  const float* Wk = (const float*)d_in[4];
  const float* Wv = (const float*)d_in[5];
  const float* Wo = (const float*)d_in[6];
  float* out = (float*)d_out;

  __bf16* base = (__bf16*)d_ws;
  __bf16* Qbf = base;                    // 8388608
  __bf16* Kbf = base + 8388608;
  __bf16* Vbf = base + 16777216;
  __bf16* Wqb = base + 25165824;         // 1048576 each
  __bf16* Wkb = base + 26214400;
  __bf16* Wvb = base + 27262976;
  __bf16* Wob = base + 28311552;
  __bf16* Qh = base + 29360128;          // [B,H,S,dk]
  __bf16* Kh = base + 37748736;          // [B,H,S,dk]
  __bf16* Vt = base + 46137344;          // [B,H,dk,S]
  __bf16* AO = Qbf;                      // aliases Qbf (dead after gemm1)

  CastArgs ca;
  ca.s[0] = Qin; ca.s[1] = Kin; ca.s[2] = Vin;
  ca.s[3] = Wq;  ca.s[4] = Wk;  ca.s[5] = Wv;  ca.s[6] = Wo;
  ca.d[0] = Qbf; ca.d[1] = Kbf; ca.d[2] = Vbf;
  ca.d[3] = Wqb; ca.d[4] = Wkb; ca.d[5] = Wvb; ca.d[6] = Wob;
  cast_kernel<<<dim3(4096, 7), 256, 0, stream>>>(ca);

  const int M = 8192, N = 1024, K = 1024;
  dim3 bb(256);
  // Q and K projections batched: grid (bm=64, bn=8, z=2), XCD = bm%8
  gemm_bt<1, __bf16><<<dim3(64, 8, 2), bb, 0, stream>>>(Qbf, Wqb, Qh,
                                                        Kbf, Wkb, Kh, M, N, K);
  // V^T: swap operands -> Vt[n][s] = sum_k Wv[n][k] * Vin[s][k]  (M=1024, N=8192)
  // grid (bn=64, bm=8): XCD = bn%8, bn indexes the large operand (Vin) -- good.
  gemm_bt<3, __bf16><<<dim3(64, 8), bb, 0, stream>>>(Wvb, Vbf, Vt,
                                                     nullptr, nullptr, nullptr,
                                                     1024, 8192, K);
  attn_kernel<<<dim3(64, 16), bb, 0, stream>>>(Qh, Kh, Vt, AO);
  gemm_bt<0, float><<<dim3(64, 8), bb, 0, stream>>>(AO, Wob, out,
                                                    nullptr, nullptr, nullptr,
                                                    M, N, K);
}